// Round 1
// baseline (1326.743 us; speedup 1.0000x reference)
//
#include <hip/hip_runtime.h>

#define BB 16
#define NN 8
#define DD 24
#define HH 48
#define WW 48
#define AA (DD*HH*WW)   // 55296
#define TOPKc 7
#define KIGN 189        // (IGNORE_RATIO+1)*TOPK

struct GT {
  float ctr[3];    // grid units (mm/4)
  float half_[3];  // mm
  float bbox[6];   // mm center(3), size(3)
  float lo[3], hi[3]; // mm
  int keep, rejected;
};

struct Accum {
  int   npos[BB];
  float pos_sum[BB];
  float shape_sum, off_sum, iou_sum;
  float per_img[BB];
};

__device__ __forceinline__ unsigned fkey(float f) {
  unsigned u = __float_as_uint(f);
  return (u & 0x80000000u) ? ~u : (u | 0x80000000u);
}
__device__ __forceinline__ float fkey_inv(unsigned k) {
  return __uint_as_float((k & 0x80000000u) ? (k & 0x7FFFFFFFu) : ~k);
}

__device__ __forceinline__ int blockReduceSumI(int v) {
  __shared__ int s[4];
  for (int off = 32; off; off >>= 1) v += __shfl_down(v, off, 64);
  if ((threadIdx.x & 63) == 0) s[threadIdx.x >> 6] = v;
  __syncthreads();
  int r = s[0] + s[1] + s[2] + s[3];
  __syncthreads();
  return r;
}
__device__ __forceinline__ float blockReduceSumF(float v) {
  __shared__ float s[4];
  for (int off = 32; off; off >>= 1) v += __shfl_down(v, off, 64);
  if ((threadIdx.x & 63) == 0) s[threadIdx.x >> 6] = v;
  __syncthreads();
  float r = s[0] + s[1] + s[2] + s[3];
  __syncthreads();
  return r;
}

// key for anchor a given ctr (grid units). SPACING=(2,1,1). Explicit fmaf so
// every loop that computes this sees bit-identical values.
__device__ __forceinline__ unsigned keyat(int a, float cz, float cy, float cx) {
  int z = a / (HH*WW);
  int r = a - z*(HH*WW);
  int y = r / WW;
  int x = r - y*WW;
  float dz = (cz - (float)z) * 2.0f;
  float dy = cy - (float)y;
  float dx = cx - (float)x;
  float d = -__builtin_fmaf(dz, dz, __builtin_fmaf(dy, dy, dx*dx));
  return fkey(d);
}

__global__ __launch_bounds__(256) void k0_init(int* pos_n, int* ign, Accum* acc) {
  const int idx = blockIdx.x*256 + threadIdx.x;
  if (idx < BB*AA) { pos_n[idx] = 0x7FFFFFFF; ign[idx] = 0; }
  if (idx < BB) { acc->npos[idx] = 0; acc->pos_sum[idx] = 0.0f; }
  if (idx == 0) { acc->shape_sum = 0.0f; acc->off_sum = 0.0f; acc->iou_sum = 0.0f; }
}

__global__ void k1_prep(const float* __restrict__ ann, GT* __restrict__ gt) {
  int i = threadIdx.x;
  if (i >= BB*NN) return;
  const float* p = ann + i*7;
  const float cz=p[0], cy=p[1], cx=p[2], sz=p[3], sy=p[4], sx=p[5], label=p[6];
  const bool has_box = label > -1.0f;
  const float loz = fmaxf(cz - sz*0.5f, 0.0f);
  const float loy = fmaxf(cy - sy*0.5f, 0.0f);
  const float lox = fmaxf(cx - sx*0.5f, 0.0f);
  const float hiz = fminf(cz + sz*0.5f, 96.0f);
  const float hiy = fminf(cy + sy*0.5f, 192.0f);
  const float hix = fminf(cx + sx*0.5f, 192.0f);
  const float nz = fmaxf(hiz - loz, 0.0f);
  const float ny = fmaxf(hiy - loy, 0.0f);
  const float nx = fmaxf(hix - lox, 0.0f);
  const float vol = nz * ny * nx;
  const float percent = vol / (sz * sy * sx);
  const bool good = (percent > 0.1f) && (vol >= 15.0f);
  const bool keep = has_box && (vol > 0.0f) && good;
  const bool rejected = has_box && (vol > 0.0f) && !good;
  GT g;
  const float ncz = loz + nz*0.5f, ncy = loy + ny*0.5f, ncx = lox + nx*0.5f;
  if (keep) {
    g.ctr[0]=ncz*0.25f; g.ctr[1]=ncy*0.25f; g.ctr[2]=ncx*0.25f;  // /stride(=4), exact
    g.half_[0]=nz*0.5f; g.half_[1]=ny*0.5f; g.half_[2]=nx*0.5f;
    g.bbox[0]=ncz; g.bbox[1]=ncy; g.bbox[2]=ncx;
    g.bbox[3]=nz;  g.bbox[4]=ny;  g.bbox[5]=nx;
  } else {
    for (int j=0;j<3;++j){ g.ctr[j]=-0.25f; g.half_[j]=-0.5f; }
    for (int j=0;j<6;++j) g.bbox[j]=-1.0f;
  }
  g.lo[0]=loz; g.lo[1]=loy; g.lo[2]=lox;
  g.hi[0]=hiz; g.hi[1]=hiy; g.hi[2]=hix;
  g.keep = keep ? 1 : 0;
  g.rejected = rejected ? 1 : 0;
  gt[i] = g;
}

// One block per (b,n): exact top-7 / top-189 selection with jax.lax.top_k
// tie semantics (value desc, index asc), via binary search on float-ordered keys.
__global__ __launch_bounds__(256) void k2_topk(const GT* __restrict__ gt,
                                               int* __restrict__ pos_n,
                                               int* __restrict__ ign) {
  const int bn = blockIdx.x;
  const int b = bn >> 3, n = bn & 7;
  const GT g = gt[bn];
  if (!g.keep) return;
  const float cz = g.ctr[0], cy = g.ctr[1], cx = g.ctr[2];

  unsigned lo7 = 0, hi7 = 0x7FFFFFFFu;   // keys of (negated) dists are <= fkey(-0.0)=0x7FFFFFFF
  unsigned lo9 = 0, hi9 = 0x7FFFFFFFu;
  for (int it = 0; it < 31; ++it) {
    unsigned mid7 = lo7 + (unsigned)(((unsigned long long)(hi7 - lo7) + 1ull) >> 1);
    unsigned mid9 = lo9 + (unsigned)(((unsigned long long)(hi9 - lo9) + 1ull) >> 1);
    int c7 = 0, c9 = 0;
    for (int a = threadIdx.x; a < AA; a += 256) {
      unsigned k = keyat(a, cz, cy, cx);
      c7 += (k >= mid7);
      c9 += (k >= mid9);
    }
    c7 = blockReduceSumI(c7);
    c9 = blockReduceSumI(c9);
    if (lo7 < hi7) { if (c7 >= TOPKc) lo7 = mid7; else hi7 = mid7 - 1; }
    if (lo9 < hi9) { if (c9 >= KIGN)  lo9 = mid9; else hi9 = mid9 - 1; }
  }
  const unsigned k7 = lo7, k9 = lo9;

  __shared__ int tc7, tc9;
  __shared__ int tl7[512], tr7[512];
  __shared__ int tl9[512], tr9[512];
  if (threadIdx.x == 0) { tc7 = 0; tc9 = 0; }
  __syncthreads();
  int cg7l = 0, cg9l = 0;
  for (int a = threadIdx.x; a < AA; a += 256) {
    unsigned k = keyat(a, cz, cy, cx);
    cg7l += (k > k7);
    cg9l += (k > k9);
    if (k == k7) { int p = atomicAdd(&tc7, 1); if (p < 512) tl7[p] = a; }
    if (k == k9 && k9 != k7) { int p = atomicAdd(&tc9, 1); if (p < 512) tl9[p] = a; }
  }
  const int cg7 = blockReduceSumI(cg7l);
  const int cg9 = blockReduceSumI(cg9l);
  __syncthreads();
  const int T7 = min(tc7, 512), T9 = min(tc9, 512);
  for (int i = threadIdx.x; i < T7; i += 256) {
    int ai = tl7[i], r = 0;
    for (int j = 0; j < T7; ++j) r += (tl7[j] < ai);
    tr7[i] = r;
  }
  for (int i = threadIdx.x; i < T9; i += 256) {
    int ai = tl9[i], r = 0;
    for (int j = 0; j < T9; ++j) r += (tl9[j] < ai);
    tr9[i] = r;
  }
  __syncthreads();

  int* pb = pos_n + (size_t)b*AA;
  int* ib = ign + (size_t)b*AA;
  for (int a = threadIdx.x; a < AA; a += 256) {
    unsigned k = keyat(a, cz, cy, cx);
    bool top = false, igf = false;
    if (k > k7) top = true;
    else if (k == k7) {
      int r = 0;
      for (int j = 0; j < T7; ++j) if (tl7[j] == a) r = tr7[j];
      int ov = cg7 + r;                 // overall rank (0-based)
      if (ov < TOPKc) top = true;
      else if (ov < KIGN) igf = true;
    } else if (k > k9) igf = true;
    else if (k == k9) {
      int r = 0;
      for (int j = 0; j < T9; ++j) if (tl9[j] == a) r = tr9[j];
      if (cg9 + r < KIGN) igf = true;
    }
    if (top) atomicMin(&pb[a], n);      // argmax over n picks FIRST n -> min
    else if (igf) ib[a] = 1;
  }
}

__global__ __launch_bounds__(256) void k3_loss(
    const float* __restrict__ cls_out, const float* __restrict__ shape_out,
    const float* __restrict__ offset_out, const GT* __restrict__ gt,
    const int* __restrict__ pos_n, const int* __restrict__ ignm,
    float* __restrict__ neg, Accum* acc) {
  __shared__ GT sg[NN];
  const int idx = blockIdx.x * 256 + threadIdx.x;   // AA%256==0 -> block-uniform b
  const int b = idx / AA;
  const int a = idx - b * AA;
  if (threadIdx.x < NN * (int)(sizeof(GT)/4))
    ((int*)sg)[threadIdx.x] = ((const int*)(gt + b*NN))[threadIdx.x];
  __syncthreads();
  const int z = a / (HH*WW);
  const int rr = a - z*(HH*WW);
  const int y = rr / WW;
  const int x = rr - y*WW;

  float gign = 0.0f;
  for (int n = 0; n < NN; ++n) {
    if (!sg[n].rejected) continue;
    if ((float)z >= floorf(sg[n].lo[0]) && (float)z < ceilf(sg[n].hi[0]) &&
        (float)y >= floorf(sg[n].lo[1]) && (float)y < ceilf(sg[n].hi[1]) &&
        (float)x >= floorf(sg[n].lo[2]) && (float)x < ceilf(sg[n].hi[2])) gign = -1.0f;
  }

  const int pn = pos_n[idx];
  const bool is_pos = (pn < NN);
  const float target = is_pos ? 1.0f : 0.0f;
  const float ignore = (ignm[idx] ? -1.0f : 0.0f) + gign;
  const float pred = cls_out[idx];
  float prob = 1.0f / (1.0f + expf(-pred));
  prob = fminf(fmaxf(prob, 1e-4f), 1.0f - 1e-4f);
  const float alpha_f = is_pos ? 0.75f : 0.25f;
  const float pt = is_pos ? (1.0f - prob) : prob;
  const float fw = alpha_f * pt * pt;
  const float bce = fmaxf(pred, 0.0f) + log1pf(expf(-fabsf(pred))) - pred * target;
  float loss = (ignore == 0.0f) ? fw * bce : 0.0f;
  if (prob < 0.8f && is_pos) loss *= 4.0f;
  neg[idx] = is_pos ? -1.0f : loss;

  const int np = blockReduceSumI(is_pos ? 1 : 0);
  const float ps = blockReduceSumF(is_pos ? loss : 0.0f);
  if (threadIdx.x == 0 && np) {
    atomicAdd(&acc->npos[b], np);
    atomicAdd(&acc->pos_sum[b], ps);
  }

  if (is_pos) {
    const GT& g = sg[pn];
    const float toz = g.ctr[0] - (float)z;
    const float toy = g.ctr[1] - (float)y;
    const float tox = g.ctr[2] - (float)x;
    const float poz = offset_out[((size_t)b*3 + 0)*AA + a];
    const float poy = offset_out[((size_t)b*3 + 1)*AA + a];
    const float pox = offset_out[((size_t)b*3 + 2)*AA + a];
    const float psz = shape_out[((size_t)b*3 + 0)*AA + a];
    const float psy = shape_out[((size_t)b*3 + 1)*AA + a];
    const float psx = shape_out[((size_t)b*3 + 2)*AA + a];
    const float off_t = fabsf(poz - toz) + fabsf(poy - toy) + fabsf(pox - tox);
    const float shp_t = fabsf(psz - g.half_[0]) + fabsf(psy - g.half_[1]) + fabsf(psx - g.half_[2]);
    // pred bbox: center=(anchor+off)*4, size=2*shape
    const float c1z = ((float)z + poz) * 4.0f;
    const float c1y = ((float)y + poy) * 4.0f;
    const float c1x = ((float)x + pox) * 4.0f;
    const float s1z = 2.0f*psz, s1y = 2.0f*psy, s1x = 2.0f*psx;
    const float lo1z = c1z - s1z*0.5f, hi1z = c1z + s1z*0.5f;
    const float lo1y = c1y - s1y*0.5f, hi1y = c1y + s1y*0.5f;
    const float lo1x = c1x - s1x*0.5f, hi1x = c1x + s1x*0.5f;
    const float c2z = g.bbox[0], c2y = g.bbox[1], c2x = g.bbox[2];
    const float s2z = g.bbox[3], s2y = g.bbox[4], s2x = g.bbox[5];
    const float lo2z = c2z - s2z*0.5f, hi2z = c2z + s2z*0.5f;
    const float lo2y = c2y - s2y*0.5f, hi2y = c2y + s2y*0.5f;
    const float lo2x = c2x - s2x*0.5f, hi2x = c2x + s2x*0.5f;
    const float iz = fmaxf(fminf(hi1z,hi2z) - fmaxf(lo1z,lo2z), 0.0f);
    const float iy = fmaxf(fminf(hi1y,hi2y) - fmaxf(lo1y,lo2y), 0.0f);
    const float ix = fmaxf(fminf(hi1x,hi2x) - fmaxf(lo1x,lo2x), 0.0f);
    const float inter = iz*iy*ix + 1e-7f;
    const float uni = s1z*s1y*s1x + s2z*s2y*s2x - inter;
    const float iou = inter / uni;
    const float ez = fmaxf(hi1z,hi2z) - fminf(lo1z,lo2z);
    const float ey = fmaxf(hi1y,hi2y) - fminf(lo1y,lo2y);
    const float ex = fmaxf(hi1x,hi2x) - fminf(lo1x,lo2x);
    const float c2d = (ez*ez + ey*ey) + ex*ex + 1e-7f;
    const float rz = (lo2z + hi2z) - (lo1z + hi1z);
    const float ry = (lo2y + hi2y) - (lo1y + hi1y);
    const float rx = (lo2x + hi2x) - (lo1x + hi1x);
    const float rho2 = ((rz*rz + ry*ry) + rx*rx) * 0.25f;
    const float diou = iou - rho2 / c2d;
    atomicAdd(&acc->shape_sum, shp_t);
    atomicAdd(&acc->off_sum, off_t);
    atomicAdd(&acc->iou_sum, diou);
  }
}

// Per image: sum of top-k hard negative losses (exact k-th-value tie handling).
__global__ __launch_bounds__(256) void k4_negsum(const float* __restrict__ neg, Accum* acc) {
  const int b = blockIdx.x;
  const float* nb = neg + (size_t)b*AA;
  const int npos = acc->npos[b];
  const int k = npos > 0 ? 100*npos : 100;
  unsigned lo = 0, hi = 0xFFFFFFFFu;
  for (int it = 0; it < 32; ++it) {
    unsigned mid = lo + (unsigned)(((unsigned long long)(hi - lo) + 1ull) >> 1);
    int c = 0;
    for (int i = threadIdx.x; i < AA; i += 256) c += (fkey(nb[i]) >= mid);
    c = blockReduceSumI(c);
    if (lo < hi) { if (c >= k) lo = mid; else hi = mid - 1; }
  }
  const unsigned kk = lo;
  const float v = fkey_inv(kk);
  int cg = 0; float sg = 0.0f;
  for (int i = threadIdx.x; i < AA; i += 256) {
    float xv = nb[i];
    if (fkey(xv) > kk) { cg++; sg += xv; }
  }
  cg = blockReduceSumI(cg);
  sg = blockReduceSumF(sg);
  if (threadIdx.x == 0) {
    float ns = (v >= 0.0f) ? (sg + (float)(k - cg) * v) : sg;  // v<0: fewer than k nonneg
    acc->per_img[b] = (acc->pos_sum[b] + ns) / fmaxf((float)npos, 1.0f);
  }
}

__global__ void k5_final(const Accum* __restrict__ acc, float* __restrict__ out) {
  float s = 0.0f; int tot = 0;
  for (int b = 0; b < BB; ++b) { s += acc->per_img[b]; tot += acc->npos[b]; }
  out[0] = s / (float)BB;
  const float denom = fmaxf((float)tot, 1.0f);
  out[1] = acc->shape_sum / (denom * 3.0f);
  out[2] = acc->off_sum / (denom * 3.0f);
  out[3] = 1.0f - acc->iou_sum / denom;
}

extern "C" void kernel_launch(void* const* d_in, const int* in_sizes, int n_in,
                              void* d_out, int out_size, void* d_ws, size_t ws_size,
                              hipStream_t stream) {
  const float* cls_out    = (const float*)d_in[0];
  const float* shape_out  = (const float*)d_in[1];
  const float* offset_out = (const float*)d_in[2];
  const float* ann        = (const float*)d_in[3];
  float* out = (float*)d_out;

  char* ws = (char*)d_ws;
  GT* gt     = (GT*)ws;                          // 128*80   = 10240 B
  Accum* acc = (Accum*)(ws + 10240);             // ~208 B
  int* pos_n = (int*)(ws + 11264);               // B*A ints = 3.54 MB
  int* ign   = pos_n + (size_t)BB*AA;            // 3.54 MB
  float* neg = (float*)(ign + (size_t)BB*AA);    // 3.54 MB

  const int nblk = (BB*AA)/256;  // 3456
  hipLaunchKernelGGL(k0_init, dim3(nblk), dim3(256), 0, stream, pos_n, ign, acc);
  hipLaunchKernelGGL(k1_prep, dim3(1), dim3(128), 0, stream, ann, gt);
  hipLaunchKernelGGL(k2_topk, dim3(BB*NN), dim3(256), 0, stream, gt, pos_n, ign);
  hipLaunchKernelGGL(k3_loss, dim3(nblk), dim3(256), 0, stream,
                     cls_out, shape_out, offset_out, gt, pos_n, ign, neg, acc);
  hipLaunchKernelGGL(k4_negsum, dim3(BB), dim3(256), 0, stream, neg, acc);
  hipLaunchKernelGGL(k5_final, dim3(1), dim3(1), 0, stream, acc, out);
}

// Round 2
// 108.203 us; speedup vs baseline: 12.2616x; 12.2616x over previous
//
#include <hip/hip_runtime.h>

#define BB 16
#define NN 8
#define DD 24
#define HH 48
#define WW 48
#define AA (DD*HH*WW)   // 55296
#define TOPKc 7
#define KIGN 189        // (IGNORE_RATIO+1)*TOPK
#define CPT 32          // ceil(13*25*25 / 256) candidates per thread

struct GT {
  float ctr[3];    // grid units (mm/4)
  float half_[3];  // mm
  float bbox[6];   // mm center(3), size(3)
  float lo[3], hi[3]; // mm
  int keep, rejected;
};

struct Accum {
  int   npos[BB];
  float pos_sum[BB];
  float shape_sum, off_sum, iou_sum;
  float per_img[BB];
};

__device__ __forceinline__ unsigned fkey(float f) {
  unsigned u = __float_as_uint(f);
  return (u & 0x80000000u) ? ~u : (u | 0x80000000u);
}
__device__ __forceinline__ float fkey_inv(unsigned k) {
  return __uint_as_float((k & 0x80000000u) ? (k & 0x7FFFFFFFu) : ~k);
}

// GT preprocessing (was k1) — pure scalar, recomputed where needed.
__device__ __forceinline__ GT prep_gt(const float* __restrict__ p) {
  const float cz=p[0], cy=p[1], cx=p[2], sz=p[3], sy=p[4], sx=p[5], label=p[6];
  const bool has_box = label > -1.0f;
  const float loz = fmaxf(cz - sz*0.5f, 0.0f);
  const float loy = fmaxf(cy - sy*0.5f, 0.0f);
  const float lox = fmaxf(cx - sx*0.5f, 0.0f);
  const float hiz = fminf(cz + sz*0.5f, 96.0f);
  const float hiy = fminf(cy + sy*0.5f, 192.0f);
  const float hix = fminf(cx + sx*0.5f, 192.0f);
  const float nz = fmaxf(hiz - loz, 0.0f);
  const float ny = fmaxf(hiy - loy, 0.0f);
  const float nx = fmaxf(hix - lox, 0.0f);
  const float vol = nz * ny * nx;
  const float percent = vol / (sz * sy * sx);
  const bool good = (percent > 0.1f) && (vol >= 15.0f);
  const bool keep = has_box && (vol > 0.0f) && good;
  const bool rejected = has_box && (vol > 0.0f) && !good;
  GT g;
  const float ncz = loz + nz*0.5f, ncy = loy + ny*0.5f, ncx = lox + nx*0.5f;
  if (keep) {
    g.ctr[0]=ncz*0.25f; g.ctr[1]=ncy*0.25f; g.ctr[2]=ncx*0.25f;
    g.half_[0]=nz*0.5f; g.half_[1]=ny*0.5f; g.half_[2]=nx*0.5f;
    g.bbox[0]=ncz; g.bbox[1]=ncy; g.bbox[2]=ncx;
    g.bbox[3]=nz;  g.bbox[4]=ny;  g.bbox[5]=nx;
  } else {
    for (int j=0;j<3;++j){ g.ctr[j]=-0.25f; g.half_[j]=-0.5f; }
    for (int j=0;j<6;++j) g.bbox[j]=-1.0f;
  }
  g.lo[0]=loz; g.lo[1]=loy; g.lo[2]=lox;
  g.hi[0]=hiz; g.hi[1]=hiy; g.hi[2]=hix;
  g.keep = keep ? 1 : 0;
  g.rejected = rejected ? 1 : 0;
  return g;
}

// single-barrier parity reduce, 256 threads (see buffer-rotation proof in notes)
__device__ __forceinline__ int redI256(int v, int par) {
  __shared__ int s[2][4];
  for (int off = 32; off; off >>= 1) v += __shfl_down(v, off, 64);
  if ((threadIdx.x & 63) == 0) s[par][threadIdx.x >> 6] = v;
  __syncthreads();
  return s[par][0] + s[par][1] + s[par][2] + s[par][3];
}
// legacy 2-barrier reduces (used once per block in k3)
__device__ __forceinline__ int blockReduceSumI(int v) {
  __shared__ int s[4];
  for (int off = 32; off; off >>= 1) v += __shfl_down(v, off, 64);
  if ((threadIdx.x & 63) == 0) s[threadIdx.x >> 6] = v;
  __syncthreads();
  int r = s[0] + s[1] + s[2] + s[3];
  __syncthreads();
  return r;
}
__device__ __forceinline__ float blockReduceSumF(float v) {
  __shared__ float s[4];
  for (int off = 32; off; off >>= 1) v += __shfl_down(v, off, 64);
  if ((threadIdx.x & 63) == 0) s[threadIdx.x >> 6] = v;
  __syncthreads();
  float r = s[0] + s[1] + s[2] + s[3];
  __syncthreads();
  return r;
}
// 1024-thread single-barrier parity reduce
__device__ __forceinline__ int redI1024(int v, int par) {
  __shared__ int s[2][16];
  for (int off = 32; off; off >>= 1) v += __shfl_down(v, off, 64);
  if ((threadIdx.x & 63) == 0) s[par][threadIdx.x >> 6] = v;
  __syncthreads();
  int r = 0;
  #pragma unroll
  for (int w = 0; w < 16; ++w) r += s[par][w];
  return r;
}
__device__ __forceinline__ float redF1024(float v) {
  __shared__ float s[16];
  for (int off = 32; off; off >>= 1) v += __shfl_down(v, off, 64);
  if ((threadIdx.x & 63) == 0) s[threadIdx.x >> 6] = v;
  __syncthreads();
  float r = 0.0f;
  #pragma unroll
  for (int w = 0; w < 16; ++w) r += s[w];
  __syncthreads();
  return r;
}

__global__ __launch_bounds__(256) void k0_init(int* pos_n, int* ign, Accum* acc) {
  const int idx = blockIdx.x*256 + threadIdx.x;
  if (idx < BB*AA) { pos_n[idx] = 0x7FFFFFFF; ign[idx] = 0; }
  if (idx < BB) { acc->npos[idx] = 0; acc->pos_sum[idx] = 0.0f; }
  if (idx == 0) { acc->shape_sum = 0.0f; acc->off_sum = 0.0f; acc->iou_sum = 0.0f; }
}

// One block per (b,n). Candidate window ±6(z)/±12(y,x) around rounded ctr
// provably contains all top-189 anchors (excluded anchors: scaled dist >= 12.5;
// window holds >= ~500 anchors within 12.5 even at a grid corner).
__global__ __launch_bounds__(256) void k2_topk(const float* __restrict__ ann,
                                               int* __restrict__ pos_n,
                                               int* __restrict__ ign) {
  const int bn = blockIdx.x;
  const int b = bn >> 3, n = bn & 7;
  const GT g = prep_gt(ann + bn*7);
  if (!g.keep) return;
  const float cz = g.ctr[0], cy = g.ctr[1], cx = g.ctr[2];

  const int rz = (int)floorf(cz + 0.5f);
  const int ry = (int)floorf(cy + 0.5f);
  const int rx = (int)floorf(cx + 0.5f);
  const int zlo = max(0, rz - 6),  zhi = min(DD - 1, rz + 6);
  const int ylo = max(0, ry - 12), yhi = min(HH - 1, ry + 12);
  const int xlo = max(0, rx - 12), xhi = min(WW - 1, rx + 12);
  const int WZ = zhi - zlo + 1, WY = yhi - ylo + 1, WX = xhi - xlo + 1;
  const int WYX = WY * WX;
  const int cnt = WZ * WYX;     // >= 7*13*13 = 1183 >= 189 always

  // register-cached candidate keys + anchor ids (static indexing via unroll)
  unsigned kk[CPT];
  int aa_[CPT];
  #pragma unroll
  for (int j = 0; j < CPT; ++j) {
    const int ci = threadIdx.x + j*256;
    const bool valid = ci < cnt;
    const int wz = ci / WYX;
    const int rem = ci - wz*WYX;
    const int wy = rem / WX;
    const int wx = rem - wy*WX;
    const int z = zlo + wz, y = ylo + wy, x = xlo + wx;
    const float dz = (cz - (float)z) * 2.0f;
    const float dy = cy - (float)y;
    const float dx = cx - (float)x;
    const float d = -__builtin_fmaf(dz, dz, __builtin_fmaf(dy, dy, dx*dx));
    kk[j] = valid ? fkey(d) : 0u;           // real keys are always > 0
    aa_[j] = (z*HH + y)*WW + x;
  }

  // fused bisection for 7th and 189th largest key (counts packed in one int)
  unsigned lo7 = 0, hi7 = 0x7FFFFFFFu;
  unsigned lo9 = 0, hi9 = 0x7FFFFFFFu;
  for (int it = 0; it < 31; ++it) {
    const unsigned mid7 = lo7 + (((hi7 - lo7) + 1u) >> 1);
    const unsigned mid9 = lo9 + (((hi9 - lo9) + 1u) >> 1);
    int c7 = 0, c9 = 0;
    #pragma unroll
    for (int j = 0; j < CPT; ++j) {
      c7 += (kk[j] >= mid7);
      c9 += (kk[j] >= mid9);
    }
    const int packed = redI256((c7 << 16) | c9, it & 1);
    c7 = packed >> 16; c9 = packed & 0xFFFF;
    if (lo7 < hi7) { if (c7 >= TOPKc) lo7 = mid7; else hi7 = mid7 - 1; }
    if (lo9 < hi9) { if (c9 >= KIGN)  lo9 = mid9; else hi9 = mid9 - 1; }
  }
  const unsigned k7 = lo7, k9 = lo9;

  // boundary-tie pass
  __shared__ int tc7, tc9;
  __shared__ int tl7[256], tr7[256];
  __shared__ int tl9[256], tr9[256];
  if (threadIdx.x == 0) { tc7 = 0; tc9 = 0; }
  __syncthreads();
  int cg7l = 0, cg9l = 0;
  #pragma unroll
  for (int j = 0; j < CPT; ++j) {
    const unsigned k = kk[j];
    cg7l += (k > k7);
    cg9l += (k > k9);
    if (k == k7) { int p = atomicAdd(&tc7, 1); if (p < 256) tl7[p] = aa_[j]; }
    if (k == k9 && k9 != k7) { int p = atomicAdd(&tc9, 1); if (p < 256) tl9[p] = aa_[j]; }
  }
  const int packed2 = redI256((cg7l << 16) | cg9l, 1);
  const int cg7 = packed2 >> 16, cg9 = packed2 & 0xFFFF;
  __syncthreads();
  const int T7 = min(tc7, 256), T9 = min(tc9, 256);
  for (int i = threadIdx.x; i < T7; i += 256) {
    int ai = tl7[i], r = 0;
    for (int j = 0; j < T7; ++j) r += (tl7[j] < ai);
    tr7[i] = r;
  }
  for (int i = threadIdx.x; i < T9; i += 256) {
    int ai = tl9[i], r = 0;
    for (int j = 0; j < T9; ++j) r += (tl9[j] < ai);
    tr9[i] = r;
  }
  __syncthreads();

  int* pb = pos_n + (size_t)b*AA;
  int* ib = ign + (size_t)b*AA;
  #pragma unroll
  for (int j = 0; j < CPT; ++j) {
    const unsigned k = kk[j];
    const int a = aa_[j];
    bool top = false, igf = false;
    if (k > k7) top = true;
    else if (k == k7) {
      int r = 0;
      for (int t = 0; t < T7; ++t) if (tl7[t] == a) r = tr7[t];
      const int ov = cg7 + r;
      if (ov < TOPKc) top = true;
      else if (ov < KIGN) igf = true;
    } else if (k > k9) igf = true;
    else if (k == k9) {
      int r = 0;
      for (int t = 0; t < T9; ++t) if (tl9[t] == a) r = tr9[t];
      if (cg9 + r < KIGN) igf = true;
    }
    if (top) atomicMin(&pb[a], n);   // argmax over n picks FIRST n -> min
    else if (igf) ib[a] = 1;
  }
}

__global__ __launch_bounds__(256) void k3_loss(
    const float* __restrict__ cls_out, const float* __restrict__ shape_out,
    const float* __restrict__ offset_out, const float* __restrict__ ann,
    const int* __restrict__ pos_n, const int* __restrict__ ignm,
    float* __restrict__ neg, Accum* acc) {
  __shared__ GT sg[NN];
  const int idx = blockIdx.x * 256 + threadIdx.x;   // AA%256==0 -> block-uniform b
  const int b = idx / AA;
  const int a = idx - b * AA;
  if (threadIdx.x < NN) sg[threadIdx.x] = prep_gt(ann + (b*NN + threadIdx.x)*7);
  __syncthreads();
  const int z = a / (HH*WW);
  const int rr = a - z*(HH*WW);
  const int y = rr / WW;
  const int x = rr - y*WW;

  float gign = 0.0f;
  for (int n = 0; n < NN; ++n) {
    if (!sg[n].rejected) continue;
    if ((float)z >= floorf(sg[n].lo[0]) && (float)z < ceilf(sg[n].hi[0]) &&
        (float)y >= floorf(sg[n].lo[1]) && (float)y < ceilf(sg[n].hi[1]) &&
        (float)x >= floorf(sg[n].lo[2]) && (float)x < ceilf(sg[n].hi[2])) gign = -1.0f;
  }

  const int pn = pos_n[idx];
  const bool is_pos = (pn < NN);
  const float target = is_pos ? 1.0f : 0.0f;
  const float ignore = (ignm[idx] ? -1.0f : 0.0f) + gign;
  const float pred = cls_out[idx];
  float prob = 1.0f / (1.0f + expf(-pred));
  prob = fminf(fmaxf(prob, 1e-4f), 1.0f - 1e-4f);
  const float alpha_f = is_pos ? 0.75f : 0.25f;
  const float pt = is_pos ? (1.0f - prob) : prob;
  const float fw = alpha_f * pt * pt;
  const float bce = fmaxf(pred, 0.0f) + log1pf(expf(-fabsf(pred))) - pred * target;
  float loss = (ignore == 0.0f) ? fw * bce : 0.0f;
  if (prob < 0.8f && is_pos) loss *= 4.0f;
  neg[idx] = is_pos ? -1.0f : loss;

  const int np = blockReduceSumI(is_pos ? 1 : 0);
  const float ps = blockReduceSumF(is_pos ? loss : 0.0f);
  if (threadIdx.x == 0 && np) {
    atomicAdd(&acc->npos[b], np);
    atomicAdd(&acc->pos_sum[b], ps);
  }

  if (is_pos) {
    const GT& g = sg[pn];
    const float toz = g.ctr[0] - (float)z;
    const float toy = g.ctr[1] - (float)y;
    const float tox = g.ctr[2] - (float)x;
    const float poz = offset_out[((size_t)b*3 + 0)*AA + a];
    const float poy = offset_out[((size_t)b*3 + 1)*AA + a];
    const float pox = offset_out[((size_t)b*3 + 2)*AA + a];
    const float psz = shape_out[((size_t)b*3 + 0)*AA + a];
    const float psy = shape_out[((size_t)b*3 + 1)*AA + a];
    const float psx = shape_out[((size_t)b*3 + 2)*AA + a];
    const float off_t = fabsf(poz - toz) + fabsf(poy - toy) + fabsf(pox - tox);
    const float shp_t = fabsf(psz - g.half_[0]) + fabsf(psy - g.half_[1]) + fabsf(psx - g.half_[2]);
    const float c1z = ((float)z + poz) * 4.0f;
    const float c1y = ((float)y + poy) * 4.0f;
    const float c1x = ((float)x + pox) * 4.0f;
    const float s1z = 2.0f*psz, s1y = 2.0f*psy, s1x = 2.0f*psx;
    const float lo1z = c1z - s1z*0.5f, hi1z = c1z + s1z*0.5f;
    const float lo1y = c1y - s1y*0.5f, hi1y = c1y + s1y*0.5f;
    const float lo1x = c1x - s1x*0.5f, hi1x = c1x + s1x*0.5f;
    const float c2z = g.bbox[0], c2y = g.bbox[1], c2x = g.bbox[2];
    const float s2z = g.bbox[3], s2y = g.bbox[4], s2x = g.bbox[5];
    const float lo2z = c2z - s2z*0.5f, hi2z = c2z + s2z*0.5f;
    const float lo2y = c2y - s2y*0.5f, hi2y = c2y + s2y*0.5f;
    const float lo2x = c2x - s2x*0.5f, hi2x = c2x + s2x*0.5f;
    const float iz = fmaxf(fminf(hi1z,hi2z) - fmaxf(lo1z,lo2z), 0.0f);
    const float iy = fmaxf(fminf(hi1y,hi2y) - fmaxf(lo1y,lo2y), 0.0f);
    const float ix = fmaxf(fminf(hi1x,hi2x) - fmaxf(lo1x,lo2x), 0.0f);
    const float inter = iz*iy*ix + 1e-7f;
    const float uni = s1z*s1y*s1x + s2z*s2y*s2x - inter;
    const float iou = inter / uni;
    const float ez = fmaxf(hi1z,hi2z) - fminf(lo1z,lo2z);
    const float ey = fmaxf(hi1y,hi2y) - fminf(lo1y,lo2y);
    const float ex = fmaxf(hi1x,hi2x) - fminf(lo1x,lo2x);
    const float c2d = (ez*ez + ey*ey) + ex*ex + 1e-7f;
    const float rz = (lo2z + hi2z) - (lo1z + hi1z);
    const float ry = (lo2y + hi2y) - (lo1y + hi1y);
    const float rx = (lo2x + hi2x) - (lo1x + hi1x);
    const float rho2 = ((rz*rz + ry*ry) + rx*rx) * 0.25f;
    const float diou = iou - rho2 / c2d;
    atomicAdd(&acc->shape_sum, shp_t);
    atomicAdd(&acc->off_sum, off_t);
    atomicAdd(&acc->iou_sum, diou);
  }
}

// Per image: sum of top-k hard negatives. Keys cached in registers (54/thread).
__global__ __launch_bounds__(1024) void k4_negsum(const float* __restrict__ neg, Accum* acc) {
  const int b = blockIdx.x;
  const float* nb = neg + (size_t)b*AA;
  const int npos = acc->npos[b];
  const int k = npos > 0 ? 100*npos : 100;

  float val[54];
  unsigned key[54];
  #pragma unroll
  for (int t = 0; t < 54; ++t) {
    val[t] = nb[threadIdx.x + t*1024];
    key[t] = fkey(val[t]);
  }

  unsigned lo = 0, hi = 0xFFFFFFFFu;
  for (int it = 0; it < 32; ++it) {
    const unsigned mid = lo + (unsigned)(((unsigned long long)(hi - lo) + 1ull) >> 1);
    int c = 0;
    #pragma unroll
    for (int t = 0; t < 54; ++t) c += (key[t] >= mid);
    c = redI1024(c, it & 1);
    if (lo < hi) { if (c >= k) lo = mid; else hi = mid - 1; }
  }
  const unsigned kk = lo;
  const float v = fkey_inv(kk);
  int cg = 0; float sg = 0.0f;
  #pragma unroll
  for (int t = 0; t < 54; ++t) {
    if (key[t] > kk) { cg++; sg += val[t]; }
  }
  cg = redI1024(cg, 0);
  sg = redF1024(sg);
  if (threadIdx.x == 0) {
    const float ns = (v >= 0.0f) ? (sg + (float)(k - cg) * v) : sg;
    acc->per_img[b] = (acc->pos_sum[b] + ns) / fmaxf((float)npos, 1.0f);
  }
}

__global__ void k5_final(const Accum* __restrict__ acc, float* __restrict__ out) {
  float s = 0.0f; int tot = 0;
  for (int b = 0; b < BB; ++b) { s += acc->per_img[b]; tot += acc->npos[b]; }
  out[0] = s / (float)BB;
  const float denom = fmaxf((float)tot, 1.0f);
  out[1] = acc->shape_sum / (denom * 3.0f);
  out[2] = acc->off_sum / (denom * 3.0f);
  out[3] = 1.0f - acc->iou_sum / denom;
}

extern "C" void kernel_launch(void* const* d_in, const int* in_sizes, int n_in,
                              void* d_out, int out_size, void* d_ws, size_t ws_size,
                              hipStream_t stream) {
  const float* cls_out    = (const float*)d_in[0];
  const float* shape_out  = (const float*)d_in[1];
  const float* offset_out = (const float*)d_in[2];
  const float* ann        = (const float*)d_in[3];
  float* out = (float*)d_out;

  char* ws = (char*)d_ws;
  Accum* acc = (Accum*)ws;                       // ~208 B
  int* pos_n = (int*)(ws + 1024);                // B*A ints = 3.54 MB
  int* ign   = pos_n + (size_t)BB*AA;            // 3.54 MB
  float* neg = (float*)(ign + (size_t)BB*AA);    // 3.54 MB

  const int nblk = (BB*AA)/256;  // 3456
  hipLaunchKernelGGL(k0_init, dim3(nblk), dim3(256), 0, stream, pos_n, ign, acc);
  hipLaunchKernelGGL(k2_topk, dim3(BB*NN), dim3(256), 0, stream, ann, pos_n, ign);
  hipLaunchKernelGGL(k3_loss, dim3(nblk), dim3(256), 0, stream,
                     cls_out, shape_out, offset_out, ann, pos_n, ign, neg, acc);
  hipLaunchKernelGGL(k4_negsum, dim3(BB), dim3(1024), 0, stream, neg, acc);
  hipLaunchKernelGGL(k5_final, dim3(1), dim3(1), 0, stream, acc, out);
}

// Round 3
// 105.168 us; speedup vs baseline: 12.6155x; 1.0289x over previous
//
#include <hip/hip_runtime.h>

#define BB 16
#define NN 8
#define DD 24
#define HH 48
#define WW 48
#define AA (DD*HH*WW)   // 55296
#define TOPKc 7
#define KIGN 189        // (IGNORE_RATIO+1)*TOPK

// fixed candidate window (shifted to stay in-grid): 13 x 25 x 25 = 8125
#define WZC 13
#define WYC 25
#define WXC 25
#define WYXC (WYC*WXC)          // 625
#define CNTC (WZC*WYXC)         // 8125
#define CPT 32                  // 32*256 = 8192 >= 8125

struct GT {
  float ctr[3];    // grid units (mm/4)
  float half_[3];  // mm
  float bbox[6];   // mm center(3), size(3)
  float lo[3], hi[3]; // mm
  int keep, rejected;
};

struct Accum {
  int   npos[BB];
  float pos_sum[BB];
  float shape_sum, off_sum, iou_sum;
  float per_img[BB];
};

__device__ __forceinline__ unsigned fkey(float f) {
  unsigned u = __float_as_uint(f);
  return (u & 0x80000000u) ? ~u : (u | 0x80000000u);
}
__device__ __forceinline__ float fkey_inv(unsigned k) {
  return __uint_as_float((k & 0x80000000u) ? (k & 0x7FFFFFFFu) : ~k);
}

__device__ __forceinline__ GT prep_gt(const float* __restrict__ p) {
  const float cz=p[0], cy=p[1], cx=p[2], sz=p[3], sy=p[4], sx=p[5], label=p[6];
  const bool has_box = label > -1.0f;
  const float loz = fmaxf(cz - sz*0.5f, 0.0f);
  const float loy = fmaxf(cy - sy*0.5f, 0.0f);
  const float lox = fmaxf(cx - sx*0.5f, 0.0f);
  const float hiz = fminf(cz + sz*0.5f, 96.0f);
  const float hiy = fminf(cy + sy*0.5f, 192.0f);
  const float hix = fminf(cx + sx*0.5f, 192.0f);
  const float nz = fmaxf(hiz - loz, 0.0f);
  const float ny = fmaxf(hiy - loy, 0.0f);
  const float nx = fmaxf(hix - lox, 0.0f);
  const float vol = nz * ny * nx;
  const float percent = vol / (sz * sy * sx);
  const bool good = (percent > 0.1f) && (vol >= 15.0f);
  const bool keep = has_box && (vol > 0.0f) && good;
  const bool rejected = has_box && (vol > 0.0f) && !good;
  GT g;
  const float ncz = loz + nz*0.5f, ncy = loy + ny*0.5f, ncx = lox + nx*0.5f;
  if (keep) {
    g.ctr[0]=ncz*0.25f; g.ctr[1]=ncy*0.25f; g.ctr[2]=ncx*0.25f;
    g.half_[0]=nz*0.5f; g.half_[1]=ny*0.5f; g.half_[2]=nx*0.5f;
    g.bbox[0]=ncz; g.bbox[1]=ncy; g.bbox[2]=ncx;
    g.bbox[3]=nz;  g.bbox[4]=ny;  g.bbox[5]=nx;
  } else {
    for (int j=0;j<3;++j){ g.ctr[j]=-0.25f; g.half_[j]=-0.5f; }
    for (int j=0;j<6;++j) g.bbox[j]=-1.0f;
  }
  g.lo[0]=loz; g.lo[1]=loy; g.lo[2]=lox;
  g.hi[0]=hiz; g.hi[1]=hiy; g.hi[2]=hix;
  g.keep = keep ? 1 : 0;
  g.rejected = rejected ? 1 : 0;
  return g;
}

// single-barrier parity reduce, 256 threads
__device__ __forceinline__ int redI256(int v, int par) {
  __shared__ int s[2][4];
  for (int off = 32; off; off >>= 1) v += __shfl_down(v, off, 64);
  if ((threadIdx.x & 63) == 0) s[par][threadIdx.x >> 6] = v;
  __syncthreads();
  return s[par][0] + s[par][1] + s[par][2] + s[par][3];
}
__device__ __forceinline__ int blockReduceSumI(int v) {
  __shared__ int s[4];
  for (int off = 32; off; off >>= 1) v += __shfl_down(v, off, 64);
  if ((threadIdx.x & 63) == 0) s[threadIdx.x >> 6] = v;
  __syncthreads();
  int r = s[0] + s[1] + s[2] + s[3];
  __syncthreads();
  return r;
}
__device__ __forceinline__ float blockReduceSumF(float v) {
  __shared__ float s[4];
  for (int off = 32; off; off >>= 1) v += __shfl_down(v, off, 64);
  if ((threadIdx.x & 63) == 0) s[threadIdx.x >> 6] = v;
  __syncthreads();
  float r = s[0] + s[1] + s[2] + s[3];
  __syncthreads();
  return r;
}
__device__ __forceinline__ int redI1024(int v, int par) {
  __shared__ int s[2][16];
  for (int off = 32; off; off >>= 1) v += __shfl_down(v, off, 64);
  if ((threadIdx.x & 63) == 0) s[par][threadIdx.x >> 6] = v;
  __syncthreads();
  int r = 0;
  #pragma unroll
  for (int w = 0; w < 16; ++w) r += s[par][w];
  return r;
}
__device__ __forceinline__ float redF1024(float v) {
  __shared__ float s[16];
  for (int off = 32; off; off >>= 1) v += __shfl_down(v, off, 64);
  if ((threadIdx.x & 63) == 0) s[threadIdx.x >> 6] = v;
  __syncthreads();
  float r = 0.0f;
  #pragma unroll
  for (int w = 0; w < 16; ++w) r += s[w];
  __syncthreads();
  return r;
}

__global__ __launch_bounds__(256) void k0_init(int* pos_n, int* ign, Accum* acc) {
  const int idx = blockIdx.x*256 + threadIdx.x;
  if (idx < BB*AA) { pos_n[idx] = 0x7FFFFFFF; ign[idx] = 0; }
  if (idx < BB) { acc->npos[idx] = 0; acc->pos_sum[idx] = 0.0f; }
  if (idx == 0) { acc->shape_sum = 0.0f; acc->off_sum = 0.0f; acc->iou_sum = 0.0f; }
}

// One block per (b,n). Fixed 13x25x25 window (origin clamped in-grid) provably
// contains every anchor at distance <= the 189th-NN radius (corner-case R<=9.5
// scaled; window half-extents 12(y,x)/6(z) with <=0.5 rounding slack).
// __launch_bounds__(256,1): 512-VGPR budget so kk[]/aa_[] stay in registers.
__global__ __launch_bounds__(256, 1) void k2_topk(const float* __restrict__ ann,
                                                  int* __restrict__ pos_n,
                                                  int* __restrict__ ign) {
  const int bn = blockIdx.x;
  const int b = bn >> 3, n = bn & 7;
  const GT g = prep_gt(ann + bn*7);
  if (!g.keep) return;
  const float cz = g.ctr[0], cy = g.ctr[1], cx = g.ctr[2];

  const int rz = (int)floorf(cz + 0.5f);
  const int ry = (int)floorf(cy + 0.5f);
  const int rx = (int)floorf(cx + 0.5f);
  const int zlo = min(max(rz - 6, 0),  DD - WZC);
  const int ylo = min(max(ry - 12, 0), HH - WYC);
  const int xlo = min(max(rx - 12, 0), WW - WXC);

  unsigned kk[CPT];
  int aa_[CPT];
  #pragma unroll
  for (int j = 0; j < CPT; ++j) {
    const int ci = threadIdx.x + j*256;
    const int wz = ci / WYXC;               // compile-time consts -> magic mul
    const int rem = ci - wz*WYXC;
    const int wy = rem / WXC;
    const int wx = rem - wy*WXC;
    const int z = zlo + wz, y = ylo + wy, x = xlo + wx;
    const float dz = (cz - (float)z) * 2.0f;
    const float dy = cy - (float)y;
    const float dx = cx - (float)x;
    const float d = -__builtin_fmaf(dz, dz, __builtin_fmaf(dy, dy, dx*dx));
    kk[j] = (ci < CNTC) ? fkey(d) : 0u;     // real keys always > 0
    aa_[j] = (z*HH + y)*WW + x;
  }

  unsigned lo7 = 0, hi7 = 0x7FFFFFFFu;
  unsigned lo9 = 0, hi9 = 0x7FFFFFFFu;
  for (int it = 0; it < 31; ++it) {
    const unsigned mid7 = lo7 + (((hi7 - lo7) + 1u) >> 1);
    const unsigned mid9 = lo9 + (((hi9 - lo9) + 1u) >> 1);
    int c7 = 0, c9 = 0;
    #pragma unroll
    for (int j = 0; j < CPT; ++j) {
      c7 += (kk[j] >= mid7);
      c9 += (kk[j] >= mid9);
    }
    const int packed = redI256((c7 << 16) | c9, it & 1);
    c7 = packed >> 16; c9 = packed & 0xFFFF;
    if (lo7 < hi7) { if (c7 >= TOPKc) lo7 = mid7; else hi7 = mid7 - 1; }
    if (lo9 < hi9) { if (c9 >= KIGN)  lo9 = mid9; else hi9 = mid9 - 1; }
  }
  const unsigned k7 = lo7, k9 = lo9;

  __shared__ int tc7, tc9;
  __shared__ int tl7[256], tr7[256];
  __shared__ int tl9[256], tr9[256];
  if (threadIdx.x == 0) { tc7 = 0; tc9 = 0; }
  __syncthreads();
  int cg7l = 0, cg9l = 0;
  #pragma unroll
  for (int j = 0; j < CPT; ++j) {
    const unsigned k = kk[j];
    cg7l += (k > k7);
    cg9l += (k > k9);
    if (k == k7) { int p = atomicAdd(&tc7, 1); if (p < 256) tl7[p] = aa_[j]; }
    if (k == k9 && k9 != k7) { int p = atomicAdd(&tc9, 1); if (p < 256) tl9[p] = aa_[j]; }
  }
  const int packed2 = redI256((cg7l << 16) | cg9l, 1);
  const int cg7 = packed2 >> 16, cg9 = packed2 & 0xFFFF;
  __syncthreads();
  const int T7 = min(tc7, 256), T9 = min(tc9, 256);
  for (int i = threadIdx.x; i < T7; i += 256) {
    int ai = tl7[i], r = 0;
    for (int j = 0; j < T7; ++j) r += (tl7[j] < ai);
    tr7[i] = r;
  }
  for (int i = threadIdx.x; i < T9; i += 256) {
    int ai = tl9[i], r = 0;
    for (int j = 0; j < T9; ++j) r += (tl9[j] < ai);
    tr9[i] = r;
  }
  __syncthreads();

  int* pb = pos_n + (size_t)b*AA;
  int* ib = ign + (size_t)b*AA;
  #pragma unroll
  for (int j = 0; j < CPT; ++j) {
    const unsigned k = kk[j];
    const int a = aa_[j];
    bool top = false, igf = false;
    if (k > k7) top = true;
    else if (k == k7) {
      int r = 0;
      for (int t = 0; t < T7; ++t) if (tl7[t] == a) r = tr7[t];
      const int ov = cg7 + r;
      if (ov < TOPKc) top = true;
      else if (ov < KIGN) igf = true;
    } else if (k > k9) igf = true;
    else if (k == k9) {
      int r = 0;
      for (int t = 0; t < T9; ++t) if (tl9[t] == a) r = tr9[t];
      if (cg9 + r < KIGN) igf = true;
    }
    if (top) atomicMin(&pb[a], n);   // argmax over n picks FIRST n -> min
    else if (igf) ib[a] = 1;
  }
}

__global__ __launch_bounds__(256) void k3_loss(
    const float* __restrict__ cls_out, const float* __restrict__ shape_out,
    const float* __restrict__ offset_out, const float* __restrict__ ann,
    const int* __restrict__ pos_n, const int* __restrict__ ignm,
    float* __restrict__ neg, Accum* acc) {
  __shared__ GT sg[NN];
  const int idx = blockIdx.x * 256 + threadIdx.x;   // AA%256==0 -> block-uniform b
  const int b = idx / AA;
  const int a = idx - b * AA;
  if (threadIdx.x < NN) sg[threadIdx.x] = prep_gt(ann + (b*NN + threadIdx.x)*7);
  __syncthreads();
  const int z = a / (HH*WW);
  const int rr = a - z*(HH*WW);
  const int y = rr / WW;
  const int x = rr - y*WW;

  float gign = 0.0f;
  for (int n = 0; n < NN; ++n) {
    if (!sg[n].rejected) continue;
    if ((float)z >= floorf(sg[n].lo[0]) && (float)z < ceilf(sg[n].hi[0]) &&
        (float)y >= floorf(sg[n].lo[1]) && (float)y < ceilf(sg[n].hi[1]) &&
        (float)x >= floorf(sg[n].lo[2]) && (float)x < ceilf(sg[n].hi[2])) gign = -1.0f;
  }

  const int pn = pos_n[idx];
  const bool is_pos = (pn < NN);
  const float target = is_pos ? 1.0f : 0.0f;
  const float ignore = (ignm[idx] ? -1.0f : 0.0f) + gign;
  const float pred = cls_out[idx];
  float prob = 1.0f / (1.0f + expf(-pred));
  prob = fminf(fmaxf(prob, 1e-4f), 1.0f - 1e-4f);
  const float alpha_f = is_pos ? 0.75f : 0.25f;
  const float pt = is_pos ? (1.0f - prob) : prob;
  const float fw = alpha_f * pt * pt;
  const float bce = fmaxf(pred, 0.0f) + log1pf(expf(-fabsf(pred))) - pred * target;
  float loss = (ignore == 0.0f) ? fw * bce : 0.0f;
  if (prob < 0.8f && is_pos) loss *= 4.0f;
  neg[idx] = is_pos ? -1.0f : loss;

  const int np = blockReduceSumI(is_pos ? 1 : 0);
  const float ps = blockReduceSumF(is_pos ? loss : 0.0f);
  if (threadIdx.x == 0 && np) {
    atomicAdd(&acc->npos[b], np);
    atomicAdd(&acc->pos_sum[b], ps);
  }

  if (is_pos) {
    const GT& g = sg[pn];
    const float toz = g.ctr[0] - (float)z;
    const float toy = g.ctr[1] - (float)y;
    const float tox = g.ctr[2] - (float)x;
    const float poz = offset_out[((size_t)b*3 + 0)*AA + a];
    const float poy = offset_out[((size_t)b*3 + 1)*AA + a];
    const float pox = offset_out[((size_t)b*3 + 2)*AA + a];
    const float psz = shape_out[((size_t)b*3 + 0)*AA + a];
    const float psy = shape_out[((size_t)b*3 + 1)*AA + a];
    const float psx = shape_out[((size_t)b*3 + 2)*AA + a];
    const float off_t = fabsf(poz - toz) + fabsf(poy - toy) + fabsf(pox - tox);
    const float shp_t = fabsf(psz - g.half_[0]) + fabsf(psy - g.half_[1]) + fabsf(psx - g.half_[2]);
    const float c1z = ((float)z + poz) * 4.0f;
    const float c1y = ((float)y + poy) * 4.0f;
    const float c1x = ((float)x + pox) * 4.0f;
    const float s1z = 2.0f*psz, s1y = 2.0f*psy, s1x = 2.0f*psx;
    const float lo1z = c1z - s1z*0.5f, hi1z = c1z + s1z*0.5f;
    const float lo1y = c1y - s1y*0.5f, hi1y = c1y + s1y*0.5f;
    const float lo1x = c1x - s1x*0.5f, hi1x = c1x + s1x*0.5f;
    const float c2z = g.bbox[0], c2y = g.bbox[1], c2x = g.bbox[2];
    const float s2z = g.bbox[3], s2y = g.bbox[4], s2x = g.bbox[5];
    const float lo2z = c2z - s2z*0.5f, hi2z = c2z + s2z*0.5f;
    const float lo2y = c2y - s2y*0.5f, hi2y = c2y + s2y*0.5f;
    const float lo2x = c2x - s2x*0.5f, hi2x = c2x + s2x*0.5f;
    const float iz = fmaxf(fminf(hi1z,hi2z) - fmaxf(lo1z,lo2z), 0.0f);
    const float iy = fmaxf(fminf(hi1y,hi2y) - fmaxf(lo1y,lo2y), 0.0f);
    const float ix = fmaxf(fminf(hi1x,hi2x) - fmaxf(lo1x,lo2x), 0.0f);
    const float inter = iz*iy*ix + 1e-7f;
    const float uni = s1z*s1y*s1x + s2z*s2y*s2x - inter;
    const float iou = inter / uni;
    const float ez = fmaxf(hi1z,hi2z) - fminf(lo1z,lo2z);
    const float ey = fmaxf(hi1y,hi2y) - fminf(lo1y,lo2y);
    const float ex = fmaxf(hi1x,hi2x) - fminf(lo1x,lo2x);
    const float c2d = (ez*ez + ey*ey) + ex*ex + 1e-7f;
    const float rz2 = (lo2z + hi2z) - (lo1z + hi1z);
    const float ry2 = (lo2y + hi2y) - (lo1y + hi1y);
    const float rx2 = (lo2x + hi2x) - (lo1x + hi1x);
    const float rho2 = ((rz2*rz2 + ry2*ry2) + rx2*rx2) * 0.25f;
    const float diou = iou - rho2 / c2d;
    atomicAdd(&acc->shape_sum, shp_t);
    atomicAdd(&acc->off_sum, off_t);
    atomicAdd(&acc->iou_sum, diou);
  }
}

// Per image: sum of top-k hard negatives. Keys ONLY in registers (54/thread,
// values recovered via fkey_inv bijection) -> ~80 VGPR, no spill at
// __launch_bounds__(1024,4) (128-VGPR budget).
__global__ __launch_bounds__(1024, 4) void k4_negsum(const float* __restrict__ neg, Accum* acc) {
  const int b = blockIdx.x;
  const float* nb = neg + (size_t)b*AA;
  const int npos = acc->npos[b];
  const int k = npos > 0 ? 100*npos : 100;

  unsigned key[54];
  #pragma unroll
  for (int t = 0; t < 54; ++t) key[t] = fkey(nb[threadIdx.x + t*1024]);

  unsigned lo = 0, hi = 0xFFFFFFFFu;
  for (int it = 0; it < 32; ++it) {
    const unsigned mid = lo + (unsigned)(((unsigned long long)(hi - lo) + 1ull) >> 1);
    int c = 0;
    #pragma unroll
    for (int t = 0; t < 54; ++t) c += (key[t] >= mid);
    c = redI1024(c, it & 1);
    if (lo < hi) { if (c >= k) lo = mid; else hi = mid - 1; }
  }
  const unsigned kk = lo;
  const float v = fkey_inv(kk);
  int cg = 0; float sg = 0.0f;
  #pragma unroll
  for (int t = 0; t < 54; ++t) {
    if (key[t] > kk) { cg++; sg += fkey_inv(key[t]); }
  }
  cg = redI1024(cg, 0);
  sg = redF1024(sg);
  if (threadIdx.x == 0) {
    const float ns = (v >= 0.0f) ? (sg + (float)(k - cg) * v) : sg;
    acc->per_img[b] = (acc->pos_sum[b] + ns) / fmaxf((float)npos, 1.0f);
  }
}

__global__ void k5_final(const Accum* __restrict__ acc, float* __restrict__ out) {
  float s = 0.0f; int tot = 0;
  for (int b = 0; b < BB; ++b) { s += acc->per_img[b]; tot += acc->npos[b]; }
  out[0] = s / (float)BB;
  const float denom = fmaxf((float)tot, 1.0f);
  out[1] = acc->shape_sum / (denom * 3.0f);
  out[2] = acc->off_sum / (denom * 3.0f);
  out[3] = 1.0f - acc->iou_sum / denom;
}

extern "C" void kernel_launch(void* const* d_in, const int* in_sizes, int n_in,
                              void* d_out, int out_size, void* d_ws, size_t ws_size,
                              hipStream_t stream) {
  const float* cls_out    = (const float*)d_in[0];
  const float* shape_out  = (const float*)d_in[1];
  const float* offset_out = (const float*)d_in[2];
  const float* ann        = (const float*)d_in[3];
  float* out = (float*)d_out;

  char* ws = (char*)d_ws;
  Accum* acc = (Accum*)ws;                       // ~208 B
  int* pos_n = (int*)(ws + 1024);                // B*A ints = 3.54 MB
  int* ign   = pos_n + (size_t)BB*AA;            // 3.54 MB
  float* neg = (float*)(ign + (size_t)BB*AA);    // 3.54 MB

  const int nblk = (BB*AA)/256;  // 3456
  hipLaunchKernelGGL(k0_init, dim3(nblk), dim3(256), 0, stream, pos_n, ign, acc);
  hipLaunchKernelGGL(k2_topk, dim3(BB*NN), dim3(256), 0, stream, ann, pos_n, ign);
  hipLaunchKernelGGL(k3_loss, dim3(nblk), dim3(256), 0, stream,
                     cls_out, shape_out, offset_out, ann, pos_n, ign, neg, acc);
  hipLaunchKernelGGL(k4_negsum, dim3(BB), dim3(1024), 0, stream, neg, acc);
  hipLaunchKernelGGL(k5_final, dim3(1), dim3(1), 0, stream, acc, out);
}